// Round 10
// baseline (317.290 us; speedup 1.0000x reference)
//
#include <hip/hip_runtime.h>
#include <hip/hip_bf16.h>
#include <cstdint>
#include <math.h>

#define NB 4
#define NN 512
#define DH 128
#define NHEADS 8
#define NHID 16
#define SLOPE 0.2f

// ---- pack adjacency bitmasks + zero the atomic output target ----
__global__ __launch_bounds__(256) void pack_adj_kernel(
    const int* __restrict__ adj, uint32_t* __restrict__ adjb, float* __restrict__ out)
{
    const int gid = blockIdx.x * 256 + threadIdx.x;      // 0..32767
    const int row = gid >> 4, w = gid & 15;
    const int4* p = (const int4*)(adj + (size_t)row * NN + w * 32);
    uint32_t m = 0;
#pragma unroll
    for (int c = 0; c < 8; ++c) {
        const int4 v = p[c];
        m |= (v.x ? 1u : 0u) << (c * 4 + 0);
        m |= (v.y ? 1u : 0u) << (c * 4 + 1);
        m |= (v.z ? 1u : 0u) << (c * 4 + 2);
        m |= (v.w ? 1u : 0u) << (c * 4 + 3);
    }
    adjb[gid] = m;
    if (gid < NB * NN) out[gid] = 0.f;
}

// ---- projection: 4 rows/block, head-major output via LDS transpose ----
// Compute (W-column per thread) as before, then stage to LDS and write
// gl/gr with contiguous 64-float runs (fixes R5-R8's stride-64B scatter).
__global__ __launch_bounds__(256) void proj_kernel(
    const float* __restrict__ h, const float* __restrict__ X,
    const float* __restrict__ Win,
    const float* __restrict__ Wl, const float* __restrict__ Wr,
    float* __restrict__ gl, float* __restrict__ gr)
{
    __shared__ __align__(16) float s_h[4 * DH];
    __shared__ float s_o[2 * 8 * 65];      // [side][hh][r*16+f], pad 65
    const int bn0 = blockIdx.x * 4;
    const int b = bn0 >> 9, n0 = bn0 & 511;
    const int t = threadIdx.x;

    if (X) {
        if (t < DH) {
            const float w0 = Win[t], w1 = Win[DH + t];
#pragma unroll
            for (int r = 0; r < 4; ++r)
                s_h[r * DH + t] = X[(bn0 + r) * 2] * w0 + X[(bn0 + r) * 2 + 1] * w1;
        }
    } else {
        for (int idx = t; idx < 4 * DH; idx += 256)
            s_h[idx] = h[(size_t)bn0 * DH + idx];
    }
    __syncthreads();

    const float* Wm = (t < DH) ? Wl : Wr;      // wave-uniform split
    const int f128 = t & 127;
    float acc[4] = {0.f, 0.f, 0.f, 0.f};
    float w[8];
#pragma unroll
    for (int u = 0; u < 8; ++u) w[u] = Wm[u * DH + f128];
    for (int k = 0; k < DH; k += 8) {          // reg double-buffered prefetch
        float wn[8];
        const bool more = (k + 8 < DH);
        if (more) {
#pragma unroll
            for (int u = 0; u < 8; ++u) wn[u] = Wm[(k + 8 + u) * DH + f128];
        }
#pragma unroll
        for (int r = 0; r < 4; ++r) {
            const float4 h0 = *(const float4*)&s_h[r * DH + k];
            const float4 h1 = *(const float4*)&s_h[r * DH + k + 4];
            acc[r] += h0.x * w[0] + h0.y * w[1] + h0.z * w[2] + h0.w * w[3]
                    + h1.x * w[4] + h1.y * w[5] + h1.z * w[6] + h1.w * w[7];
        }
        if (more) {
#pragma unroll
            for (int u = 0; u < 8; ++u) w[u] = wn[u];
        }
    }
    {   // stage: s_o[side*520 + hh*65 + r*16 + f]
        const int side = (t >= DH), hh = f128 >> 4, f = f128 & 15;
        float* so = s_o + side * 520 + hh * 65;
#pragma unroll
        for (int r = 0; r < 4; ++r) so[r * 16 + f] = acc[r];
    }
    __syncthreads();
    {   // coalesced write: 1024 floats, 64-float contiguous runs
#pragma unroll
        for (int itw = 0; itw < 4; ++itw) {
            const int idx  = itw * 256 + t;        // 0..1023
            const int side = idx >> 9;
            const int rem  = idx & 511;            // hh*64 + rf
            const int hh   = rem >> 6, rf = rem & 63;
            float* dst = (side ? gr : gl)
                       + ((size_t)(b * NHEADS + hh) * NN + n0) * NHID + rf;
            *dst = s_o[side * 520 + hh * 65 + rf];
        }
    }
}

// ---- attention: block = (b, head, 32-row i-tile); 256 thr; 4 rows/thread ----
// il = t&7 owns rows {il, il+8, il+16, il+24}; js = t>>3 owns 16-j slice.
// Slice-major LDS (stride 260) -> conflict-free 8-address broadcasts.
// No-max softmax: scores bounded (|e| << 88), p = mask ? exp(s) : 0,
// normalize by the merged sum at the end.
__global__ __launch_bounds__(256) void attn_kernel(
    const float* __restrict__ gl, const float* __restrict__ gr,
    const uint32_t* __restrict__ adjb, const float* __restrict__ a_vec,
    float* __restrict__ h_out,
    const float* __restrict__ Wout, float* __restrict__ out)
{
    __shared__ __align__(16) float smem[17216];   // 68864 B -> 2 blocks/CU
    float* s_gl  = smem;                 // 32 slices * 260
    float* s_gr  = smem + 8320;
    float* s_l   = smem + 16640;         // [32]
    float* s_acc = smem + 16672;         // [32 i][17]

    const int blk = blockIdx.x;          // (b*8+hh)*16 + it
    const int it = blk & 15;
    const int bh = blk >> 4;
    const int b  = bh >> 3, hh = bh & 7;
    const int i0 = it * 32;
    const int t  = threadIdx.x;
    const int il = t & 7;
    const int js = t >> 3;

    {   // stage head planes, slice-major swizzle (wave-contiguous LDS writes)
        const float4* pgl = (const float4*)(gl + (size_t)bh * NN * NHID);
        const float4* pgr = (const float4*)(gr + (size_t)bh * NN * NHID);
#pragma unroll
        for (int k = 0; k < 8; ++k) {
            const int g4 = k * 256 + t;            // 0..2047 float4
            const int row = g4 >> 2, q = g4 & 3;
            const int dw = (row >> 4) * 260 + (row & 15) * 16 + q * 4;
            *(float4*)(s_gl + dw) = pgl[g4];
            *(float4*)(s_gr + dw) = pgr[g4];
        }
        if (t < 32) s_l[t] = 0.f;
        for (int idx = t; idx < 544; idx += 256) s_acc[idx] = 0.f;
    }
    float a[16];
#pragma unroll
    for (int q = 0; q < 16; ++q) a[q] = a_vec[q];   // uniform -> scalar loads
    uint32_t msk[4];
#pragma unroll
    for (int r = 0; r < 4; ++r) {
        const int i = i0 + il + r * 8;
        msk[r] = (adjb[((size_t)(b * NN + i)) * 16 + (js >> 1)] >> ((js & 1) * 16)) & 0xFFFFu;
    }
    __syncthreads();

    float gri[4][16];
#pragma unroll
    for (int r = 0; r < 4; ++r) {
        const int i = i0 + il + r * 8;
        const float* pr = s_gr + (i >> 4) * 260 + (i & 15) * 16;
#pragma unroll
        for (int q = 0; q < 4; ++q) {
            const float4 v = *(const float4*)(pr + q * 4);
            gri[r][4*q+0] = v.x; gri[r][4*q+1] = v.y;
            gri[r][4*q+2] = v.z; gri[r][4*q+3] = v.w;
        }
    }

    float lrow[4] = {0.f, 0.f, 0.f, 0.f};
    float acc[4][16];
#pragma unroll
    for (int r = 0; r < 4; ++r)
#pragma unroll
        for (int f = 0; f < 16; ++f) acc[r][f] = 0.f;

    const float* sgl = s_gl + js * 260;
    const float* sgr = s_gr + js * 260;

    for (int jj = 0; jj < 16; ++jj) {
        float4 G[4];
#pragma unroll
        for (int q = 0; q < 4; ++q) G[q] = *(const float4*)(sgl + jj * 16 + q * 4);
        float p[4];
#pragma unroll
        for (int r = 0; r < 4; ++r) {
            float s = 0.f;
#pragma unroll
            for (int q = 0; q < 4; ++q) {
                float v;
                v = G[q].x + gri[r][4*q+0]; v = fmaxf(v, SLOPE * v); s += v * a[4*q+0];
                v = G[q].y + gri[r][4*q+1]; v = fmaxf(v, SLOPE * v); s += v * a[4*q+1];
                v = G[q].z + gri[r][4*q+2]; v = fmaxf(v, SLOPE * v); s += v * a[4*q+2];
                v = G[q].w + gri[r][4*q+3]; v = fmaxf(v, SLOPE * v); s += v * a[4*q+3];
            }
            p[r] = ((msk[r] >> jj) & 1u) ? __expf(s) : 0.f;   // no-max softmax
            lrow[r] += p[r];
        }
        float4 R[4];
#pragma unroll
        for (int q = 0; q < 4; ++q) R[q] = *(const float4*)(sgr + jj * 16 + q * 4);
#pragma unroll
        for (int r = 0; r < 4; ++r) {
            acc[r][0]  += p[r] * R[0].x; acc[r][1]  += p[r] * R[0].y;
            acc[r][2]  += p[r] * R[0].z; acc[r][3]  += p[r] * R[0].w;
            acc[r][4]  += p[r] * R[1].x; acc[r][5]  += p[r] * R[1].y;
            acc[r][6]  += p[r] * R[1].z; acc[r][7]  += p[r] * R[1].w;
            acc[r][8]  += p[r] * R[2].x; acc[r][9]  += p[r] * R[2].y;
            acc[r][10] += p[r] * R[2].z; acc[r][11] += p[r] * R[2].w;
            acc[r][12] += p[r] * R[3].x; acc[r][13] += p[r] * R[3].y;
            acc[r][14] += p[r] * R[3].z; acc[r][15] += p[r] * R[3].w;
        }
    }

    {   // merge: l sums, then acc with js-rotated f (no same-address contention)
#pragma unroll
        for (int r = 0; r < 4; ++r) atomicAdd(&s_l[il + r * 8], lrow[r]);
#pragma unroll
        for (int ff = 0; ff < 16; ++ff) {
            const int f = (ff + js) & 15;
#pragma unroll
            for (int r = 0; r < 4; ++r)
                atomicAdd(&s_acc[(il + r * 8) * 17 + f], acc[r][f]);
        }
    }
    __syncthreads();

    {   // epilogue: 512 (i,f) pairs, 2 per thread
#pragma unroll
        for (int half = 0; half < 2; ++half) {
            const int idx = half * 256 + t;
            const int i = idx >> 4, f = idx & 15;
            const float o = s_acc[i * 17 + f] * (1.f / s_l[i]);
            if (Wout) {
                float v = o * Wout[hh * NHID + f];
#pragma unroll
                for (int off = 8; off; off >>= 1) v += __shfl_xor(v, off);
                if (f == 0) atomicAdd(out + b * NN + i0 + i, v);
            } else {
                h_out[((size_t)(b * NN + i0 + i)) * DH + hh * NHID + f] = o;
            }
        }
    }
}

extern "C" void kernel_launch(void* const* d_in, const int* in_sizes, int n_in,
                              void* d_out, int out_size, void* d_ws, size_t ws_size,
                              hipStream_t stream) {
    const float* X    = (const float*)d_in[0];   // [4,512,2]
    const int*   adj  = (const int*)  d_in[1];   // [4,512,512]
    const float* Win  = (const float*)d_in[2];   // [2,128]
    const float* Wl   = (const float*)d_in[3];   // [3,128,128]
    const float* Wr   = (const float*)d_in[4];   // [3,128,128]
    const float* Aa   = (const float*)d_in[5];   // [3,16]
    const float* Wout = (const float*)d_in[6];   // [128,1]
    float* out = (float*)d_out;                  // [4,512] fp32

    float*    ws   = (float*)d_ws;
    float*    h    = ws;                          // 1 MB
    float*    gl   = ws + 262144;                 // 1 MB (head-major)
    float*    gr   = ws + 524288;                 // 1 MB (head-major)
    uint32_t* adjb = (uint32_t*)(ws + 786432);    // 128 KB

    pack_adj_kernel<<<NB * NN * 16 / 256, 256, 0, stream>>>(adj, adjb, out);

    for (int l = 0; l < 3; ++l) {
        proj_kernel<<<NB * NN / 4, 256, 0, stream>>>(
            h, (l == 0) ? X : nullptr, Win,
            Wl + (size_t)l * DH * DH, Wr + (size_t)l * DH * DH, gl, gr);
        attn_kernel<<<NB * NHEADS * 16, 256, 0, stream>>>(
            gl, gr, adjb, Aa + l * NHID, h,
            (l == 2) ? Wout : nullptr, out);
    }
}